// Round 14
// baseline (132.865 us; speedup 1.0000x reference)
//
#include <hip/hip_runtime.h>

// DistancePredictor on MI355X (gfx950).
// A = X@(Wi+Wd), Bm = X@(Wj-Wd)+b1 (k1, MFMA),
// P[b,i,j,h] = sum_d X[b,i,d]X[b,j,d]Wp[d,h] (k2, bf16 MFMA, triangular tiles),
// out = 0.5*(relu(W2.gelu(Ai+Bmj+P)+b2) + relu(W2.gelu(Aj+Bmi+P)+b2)), diag=0.
// R14 = R13 + epilogue de-stalling: W2 in persistent regs (was re-read from
// LDS every k of every iter); bias panel reads hoisted to 8x ds_read_b128
// issued BEFORE writeM (its ~80 VALU cyc covers LDS latency) so the 32-eval
// gelu stream is register-only; cubic log2-tail gelu poly (err +<=3e-3, margin
// 0.036); k1 grid 32->64 (was on half the CUs).

typedef __attribute__((ext_vector_type(8))) short short8;
typedef __attribute__((ext_vector_type(16))) float f32x16;
typedef __attribute__((ext_vector_type(2))) float f32x2;

#define NT 32
#define NTRI 528
#define IPB 8

__device__ __forceinline__ unsigned short f2bf(float f) {
  unsigned int u = __float_as_uint(f);
  u = (u + 0x7fffu + ((u >> 16) & 1u)) >> 16;   // RNE
  return (unsigned short)u;
}

__device__ __forceinline__ short8 pack8(float4 a, float4 b) {
  short8 r;
  r[0] = (short)f2bf(a.x); r[1] = (short)f2bf(a.y);
  r[2] = (short)f2bf(a.z); r[3] = (short)f2bf(a.w);
  r[4] = (short)f2bf(b.x); r[5] = (short)f2bf(b.y);
  r[6] = (short)f2bf(b.z); r[7] = (short)f2bf(b.w);
  return r;
}

// GELU via upper-tail exp2 form: gelu(x) = r - 2^{g(w)}*w, r=max(x,0), w=|x|.
// g(t) ~= log2(1-Phi(t)), CUBIC fit on [0,4] (exact at t=1,2.5,4): |d log2|
// <= ~0.03 where w*2^g matters => |gelu err| <= 3e-3. Monotone to t~13.
__device__ __forceinline__ f32x2 gelu_2(f32x2 x) {
  f32x2 r = __builtin_elementwise_max(x, (f32x2)0.0f);
  f32x2 w = __builtin_elementwise_fma(r, (f32x2)2.0f, -x);   // = |x|
  f32x2 g = __builtin_elementwise_fma(w, (f32x2)0.03833f, (f32x2)-0.71844f);
  g = __builtin_elementwise_fma(w, g, (f32x2)-0.97609f);
  g = __builtin_elementwise_fma(w, g, (f32x2)-1.0f);
  f32x2 f;
  f[0] = __builtin_amdgcn_exp2f(g[0]);
  f[1] = __builtin_amdgcn_exp2f(g[1]);
  return __builtin_elementwise_fma(-f, w, r);
}

// ---- k0: WsumT/WdiffT/WpT bf16 [h][d] into ws ----
__global__ void k0_prep_w(const float* __restrict__ W1, unsigned short* __restrict__ wsT) {
  int idx = blockIdx.x * 256 + threadIdx.x;          // 192 blocks exactly
  int arr = idx >> 14, rem = idx & 16383, h = rem >> 7, d = rem & 127;
  float v;
  if (arr == 0)      v = W1[d * 128 + h] + W1[(256 + d) * 128 + h];
  else if (arr == 1) v = W1[(128 + d) * 128 + h] - W1[(256 + d) * 128 + h];
  else               v = W1[(384 + d) * 128 + h];
  wsT[idx] = f2bf(v);
}

// ---- k1: A = X@Wsum, Bm = X@Wdiff + b1 via MFMA (64 blocks x 32 rows) ----
__global__ __launch_bounds__(256) void k1_ab(const float* __restrict__ X,
                                             const unsigned short* __restrict__ wsT,
                                             const float* __restrict__ b1,
                                             float* __restrict__ Aout,
                                             float* __restrict__ Bout) {
  int tid = threadIdx.x, w = tid >> 6, lane = tid & 63, jl = lane & 31, hi = lane >> 5;
  int row0 = blockIdx.x * 32;
  int c0 = w * 64;
  f32x16 a00 = (f32x16)0.f, a01 = (f32x16)0.f;
#pragma unroll
  for (int s = 0; s < 8; ++s) {
    const float* xp0 = X + (size_t)(row0 + jl) * 128 + s * 16 + hi * 8;
    short8 fa0 = pack8(*(const float4*)xp0, *(const float4*)(xp0 + 4));
    short8 fb0 = *(const short8*)(wsT + (size_t)(c0 + jl) * 128 + s * 16 + hi * 8);
    short8 fb1 = *(const short8*)(wsT + (size_t)(c0 + 32 + jl) * 128 + s * 16 + hi * 8);
    a00 = __builtin_amdgcn_mfma_f32_32x32x16_bf16(fa0, fb0, a00, 0, 0, 0);
    a01 = __builtin_amdgcn_mfma_f32_32x32x16_bf16(fa0, fb1, a01, 0, 0, 0);
  }
  bool isB = (c0 >= 128);
  float b1v0 = 0.f, b1v1 = 0.f;
  if (isB) { b1v0 = b1[c0 - 128 + jl]; b1v1 = b1[c0 - 96 + jl]; }
#pragma unroll
  for (int q = 0; q < 16; ++q) {
    int r = (q & 3) + 8 * (q >> 2) + 4 * hi;
    int bl0 = row0 + r;
    if (!isB) {
      Aout[(size_t)bl0 * 128 + c0 + jl]      = a00[q];
      Aout[(size_t)bl0 * 128 + c0 + 32 + jl] = a01[q];
    } else {
      Bout[(size_t)bl0 * 128 + c0 - 128 + jl] = a00[q] + b1v0;
      Bout[(size_t)bl0 * 128 + c0 - 96 + jl]  = a01[q] + b1v1;
    }
  }
}

union BfPack { __bf16 h[16]; short8 v[2]; };

// ---- k2: main triangular-tile kernel, 8 i-rows per block ----
__global__ __launch_bounds__(256) void k2_main(const float* __restrict__ X,
                                               const unsigned short* __restrict__ WpT,
                                               const float* __restrict__ Aws,
                                               const float* __restrict__ Bws,
                                               const float* __restrict__ W2,
                                               const float* __restrict__ b2,
                                               float* __restrict__ out) {
  __shared__ __align__(16) unsigned short Mlds[2][32 * 128];  // 16 KB, double-buffered
  __shared__ __align__(16) float Xp[IPB][128];                // 4 KB: Xi panel
  __shared__ __align__(16) float Abias[IPB][128];             // 4 KB
  __shared__ __align__(16) float Bbias[IPB][128];             // 4 KB
  __shared__ float2 osum[IPB][4][32];                         // 8 KB: per-row slots
  __shared__ float valbuf[IPB][33];                           // 1 KB => ~37.4 KB total

  int bid = blockIdx.x;
  int q4 = bid & 3;                          // i-panel quarter within the 32-tile
  int tl = bid >> 2;
  int b = tl / NTRI;
  int t = tl - b * NTRI;
  int ti = 0;
  while (t >= NT - ti) { t -= NT - ti; ++ti; }
  int tj = ti + t;
  int gi0 = ti * 32, gj0 = tj * 32;
  int giBase = gi0 + q4 * IPB;

  int tid = threadIdx.x, w = tid >> 6, lane = tid & 63, jl = lane & 31, hi = lane >> 5;
  int dseg = tid >> 5;                      // 16-d slice owned for M-build
  int gj = gj0 + jl;
  const size_t rowX = (size_t)b * 1024;

  // ---- prologue: stage Xi panel + bias panels into LDS ----
  {
    int r = tid >> 5, c = (tid & 31) * 4;    // 8 rows x 128 cols, one float4/thread/panel
    const float* xp = X   + (rowX + giBase + r) * 128 + c;
    const float* ap = Aws + (rowX + giBase + r) * 128 + c;
    const float* bp = Bws + (rowX + giBase + r) * 128 + c;
    *(float4*)(&Xp[r][c])    = *(const float4*)(xp);
    *(float4*)(&Abias[r][c]) = *(const float4*)(ap);
    *(float4*)(&Bbias[r][c]) = *(const float4*)(bp);
  }

  // persistent per-thread state (j-side + W2)
  float xj[16], bmj[16], ajv[16], w2h[16];
  {
    const float* xjp = X + (rowX + gj) * 128 + dseg * 16;
    *(float4*)(xj + 0)  = *(const float4*)(xjp + 0);
    *(float4*)(xj + 4)  = *(const float4*)(xjp + 4);
    *(float4*)(xj + 8)  = *(const float4*)(xjp + 8);
    *(float4*)(xj + 12) = *(const float4*)(xjp + 12);
  }
#pragma unroll
  for (int g = 0; g < 4; ++g) {
    int hb = 8 * g + 4 * hi + 32 * w;
    *(float4*)(bmj + 4 * g) = *(const float4*)(Bws + (rowX + gj) * 128 + hb);
    *(float4*)(ajv + 4 * g) = *(const float4*)(Aws + (rowX + gj) * 128 + hb);
    *(float4*)(w2h + 4 * g) = *(const float4*)(W2 + hb);   // loop-invariant, regs
  }
  short8 afrag[8];
#pragma unroll
  for (int s = 0; s < 8; ++s)
    afrag[s] = *(const short8*)(WpT + (size_t)(w * 32 + jl) * 128 + s * 16 + hi * 8);
  float b2s = b2[0];

  char* mB0 = (char*)Mlds[0];
  char* mB1 = (char*)Mlds[1];
  int rbase = jl * 256;
  int swz = (jl & 15) << 4;                  // 16-slot XOR involution (write==read)

  // build M(i): Xi slice from LDS broadcast * xj regs -> bf16 -> swizzled M buf
  auto writeM = [&](int i, char* mp) {
    const float* xip = &Xp[i][dseg * 16];
    float xv[16];
    *(float4*)(xv + 0)  = *(const float4*)(xip + 0);
    *(float4*)(xv + 4)  = *(const float4*)(xip + 4);
    *(float4*)(xv + 8)  = *(const float4*)(xip + 8);
    *(float4*)(xv + 12) = *(const float4*)(xip + 12);
    BfPack mb;
#pragma unroll
    for (int r = 0; r < 8; ++r) {
      f32x2 xa = { xv[2 * r], xv[2 * r + 1] };
      f32x2 xb = { xj[2 * r], xj[2 * r + 1] };
      f32x2 pr = xa * xb;
      mb.h[2 * r]     = (__bf16)pr[0];
      mb.h[2 * r + 1] = (__bf16)pr[1];
    }
    *(short8*)(mp + rbase + ((dseg * 32 + 0) ^ swz))  = mb.v[0];
    *(short8*)(mp + rbase + ((dseg * 32 + 16) ^ swz)) = mb.v[1];
  };
  auto mfmaTile = [&](const char* mr) -> f32x16 {
    f32x16 acc = (f32x16)0.0f;
#pragma unroll
    for (int s = 0; s < 8; ++s) {
      short8 bf = *(const short8*)(mr + rbase + (((2 * s + hi) * 16) ^ swz));
      acc = __builtin_amdgcn_mfma_f32_32x32x16_bf16(afrag[s], bf, acc, 0, 0, 0);
    }
    return acc;
  };
  // hoisted bias loads: 8x ds_read_b128 into regs (latency covered by writeM)
  auto loadBias = [&](int r, float* aiv, float* biv) {
#pragma unroll
    for (int g = 0; g < 4; ++g) {
      int hb = 8 * g + 4 * hi + 32 * w;
      *(float4*)(aiv + 4 * g) = *(const float4*)(&Abias[r][hb]);
      *(float4*)(biv + 4 * g) = *(const float4*)(&Bbias[r][hb]);
    }
  };
  // epilogue of row r: register-only gelu stream; writes osum[r]
  auto epilogue = [&](const f32x16& acc, const float* aiv, const float* biv, int r) {
    f32x2 o1v = { 0.f, 0.f }, o2v = { 0.f, 0.f };
#pragma unroll
    for (int k = 0; k < 8; ++k) {
      f32x2 p   = { acc[2 * k], acc[2 * k + 1] };
      f32x2 a_i = { aiv[2 * k], aiv[2 * k + 1] };
      f32x2 b_i = { biv[2 * k], biv[2 * k + 1] };
      f32x2 a_j = { ajv[2 * k], ajv[2 * k + 1] };
      f32x2 b_j = { bmj[2 * k], bmj[2 * k + 1] };
      f32x2 wv  = { w2h[2 * k], w2h[2 * k + 1] };
      f32x2 g1 = gelu_2((p + a_i) + b_j);
      f32x2 g2 = gelu_2((p + a_j) + b_i);
      o1v = __builtin_elementwise_fma(g1, wv, o1v);
      o2v = __builtin_elementwise_fma(g2, wv, o2v);
    }
    float o1 = o1v[0] + o1v[1], o2 = o2v[0] + o2v[1];
    o1 += __shfl_xor(o1, 32);
    o2 += __shfl_xor(o2, 32);
    if (lane < 32) osum[r][w][lane] = make_float2(o1, o2);
  };

  __syncthreads();                           // staging complete
  writeM(0, mB0);
  __syncthreads();                           // M(0) ready

  f32x16 accP;                               // acc of row i-1, carried
  float aivP[16], bivP[16];

#pragma unroll 1
  for (int i = 0; i < IPB; ++i) {
    // MFMA chain(i) -> accC issues first (matrix pipe, post-barrier ds_reads)
    f32x16 accC = mfmaTile((i & 1) ? mB1 : mB0);
    // bias loads for row i-1 issue now; writeM's VALU covers their latency
    if (i >= 1) loadBias(i - 1, aivP, bivP);
    if (i + 1 < IPB) writeM(i + 1, ((i + 1) & 1) ? mB1 : mB0);
    // epilogue(row i-1): register-only VALU; barrier follows it
    if (i >= 1) epilogue(accP, aivP, bivP, i - 1);
    accP = accC;
    __syncthreads();
  }
  loadBias(IPB - 1, aivP, bivP);
  epilogue(accP, aivP, bivP, IPB - 1);       // row 7; consumed after barrier
  __syncthreads();

  // ---- post-loop finalize: one output cell per thread ----
  {
    int r = tid >> 5;                        // 0..7
    int j = tid & 31;
    float2 p0 = osum[r][0][j], p1 = osum[r][1][j];
    float2 p2 = osum[r][2][j], p3 = osum[r][3][j];
    float s1 = p0.x + p1.x + p2.x + p3.x + b2s;
    float s2 = p0.y + p1.y + p2.y + p3.y + b2s;
    float v = 0.5f * (fmaxf(s1, 0.f) + fmaxf(s2, 0.f));
    int gi = giBase + r;
    if (ti == tj && gj0 + j == gi) v = 0.f;
    out[(rowX + gi) * 1024 + gj0 + j] = v;
    valbuf[r][j] = v;
  }
  __syncthreads();

  if (ti != tj && tid < 64) {                // coalesced transposed mirror flush
    int j = tid >> 1, i0 = (tid & 1) * 4;
    float4 v;
    v.x = valbuf[i0 + 0][j]; v.y = valbuf[i0 + 1][j];
    v.z = valbuf[i0 + 2][j]; v.w = valbuf[i0 + 3][j];
    *(float4*)(out + (rowX + gj0 + j) * 1024 + giBase + i0) = v;
  }
}

extern "C" void kernel_launch(void* const* d_in, const int* in_sizes, int n_in,
                              void* d_out, int out_size, void* d_ws, size_t ws_size,
                              hipStream_t stream) {
  (void)in_sizes; (void)n_in; (void)out_size; (void)ws_size;
  const float* X  = (const float*)d_in[0];   // (2,1024,128)
  const float* W1 = (const float*)d_in[1];   // (512,128)
  const float* b1 = (const float*)d_in[2];   // (128)
  const float* W2 = (const float*)d_in[3];   // (128,1)
  const float* b2 = (const float*)d_in[4];   // (1)
  float* out = (float*)d_out;                // (2,1024,1024)

  unsigned short* wsT = (unsigned short*)d_ws;
  unsigned short* WpT = wsT + 2 * 16384;
  float* Aws = (float*)((char*)d_ws + 98304);
  float* Bws = (float*)((char*)d_ws + 98304 + 1048576);

  k0_prep_w<<<192, 256, 0, stream>>>(W1, wsT);
  k1_ab<<<64, 256, 0, stream>>>(X, wsT, b1, Aws, Bws);
  k2_main<<<8 * NTRI, 256, 0, stream>>>(X, WpT, Aws, Bws, W2, b2, out);
}

// Round 15
// 125.357 us; speedup vs baseline: 1.0599x; 1.0599x over previous
//
#include <hip/hip_runtime.h>

// DistancePredictor on MI355X (gfx950).
// A = X@(Wi+Wd), Bm = X@(Wj-Wd)+b1 (k1, MFMA),
// P[b,i,j,h] = sum_d X[b,i,d]X[b,j,d]Wp[d,h] (k2, bf16 MFMA, triangular tiles),
// out = 0.5*(relu(W2.gelu(Ai+Bmj+P)+b2) + relu(W2.gelu(Aj+Bmi+P)+b2)), diag=0.
// R15 = R13's VGPR-84 shape exactly (R14's reg-hoisting cost a wave ceiling:
// 104 VGPR -> occ 20%, -10%) + cubic gelu + k1@64blocks + T5 s_setprio(1)
// around the MFMA chain (cross-block wave role diversity regime).

typedef __attribute__((ext_vector_type(8))) short short8;
typedef __attribute__((ext_vector_type(16))) float f32x16;
typedef __attribute__((ext_vector_type(2))) float f32x2;

#define NT 32
#define NTRI 528
#define IPB 8

__device__ __forceinline__ unsigned short f2bf(float f) {
  unsigned int u = __float_as_uint(f);
  u = (u + 0x7fffu + ((u >> 16) & 1u)) >> 16;   // RNE
  return (unsigned short)u;
}

__device__ __forceinline__ short8 pack8(float4 a, float4 b) {
  short8 r;
  r[0] = (short)f2bf(a.x); r[1] = (short)f2bf(a.y);
  r[2] = (short)f2bf(a.z); r[3] = (short)f2bf(a.w);
  r[4] = (short)f2bf(b.x); r[5] = (short)f2bf(b.y);
  r[6] = (short)f2bf(b.z); r[7] = (short)f2bf(b.w);
  return r;
}

// GELU via upper-tail exp2 form: gelu(x) = r - 2^{g(w)}*w, r=max(x,0), w=|x|.
// g(t) ~= log2(1-Phi(t)), cubic fit on [0,4]: |gelu err| <= ~3e-3 (margin 0.036).
__device__ __forceinline__ f32x2 gelu_2(f32x2 x) {
  f32x2 r = __builtin_elementwise_max(x, (f32x2)0.0f);
  f32x2 w = __builtin_elementwise_fma(r, (f32x2)2.0f, -x);   // = |x|
  f32x2 g = __builtin_elementwise_fma(w, (f32x2)0.03833f, (f32x2)-0.71844f);
  g = __builtin_elementwise_fma(w, g, (f32x2)-0.97609f);
  g = __builtin_elementwise_fma(w, g, (f32x2)-1.0f);
  f32x2 f;
  f[0] = __builtin_amdgcn_exp2f(g[0]);
  f[1] = __builtin_amdgcn_exp2f(g[1]);
  return __builtin_elementwise_fma(-f, w, r);
}

// ---- k0: WsumT/WdiffT/WpT bf16 [h][d] into ws ----
__global__ void k0_prep_w(const float* __restrict__ W1, unsigned short* __restrict__ wsT) {
  int idx = blockIdx.x * 256 + threadIdx.x;          // 192 blocks exactly
  int arr = idx >> 14, rem = idx & 16383, h = rem >> 7, d = rem & 127;
  float v;
  if (arr == 0)      v = W1[d * 128 + h] + W1[(256 + d) * 128 + h];
  else if (arr == 1) v = W1[(128 + d) * 128 + h] - W1[(256 + d) * 128 + h];
  else               v = W1[(384 + d) * 128 + h];
  wsT[idx] = f2bf(v);
}

// ---- k1: A = X@Wsum, Bm = X@Wdiff + b1 via MFMA (64 blocks x 32 rows) ----
__global__ __launch_bounds__(256) void k1_ab(const float* __restrict__ X,
                                             const unsigned short* __restrict__ wsT,
                                             const float* __restrict__ b1,
                                             float* __restrict__ Aout,
                                             float* __restrict__ Bout) {
  int tid = threadIdx.x, w = tid >> 6, lane = tid & 63, jl = lane & 31, hi = lane >> 5;
  int row0 = blockIdx.x * 32;
  int c0 = w * 64;
  f32x16 a00 = (f32x16)0.f, a01 = (f32x16)0.f;
#pragma unroll
  for (int s = 0; s < 8; ++s) {
    const float* xp0 = X + (size_t)(row0 + jl) * 128 + s * 16 + hi * 8;
    short8 fa0 = pack8(*(const float4*)xp0, *(const float4*)(xp0 + 4));
    short8 fb0 = *(const short8*)(wsT + (size_t)(c0 + jl) * 128 + s * 16 + hi * 8);
    short8 fb1 = *(const short8*)(wsT + (size_t)(c0 + 32 + jl) * 128 + s * 16 + hi * 8);
    a00 = __builtin_amdgcn_mfma_f32_32x32x16_bf16(fa0, fb0, a00, 0, 0, 0);
    a01 = __builtin_amdgcn_mfma_f32_32x32x16_bf16(fa0, fb1, a01, 0, 0, 0);
  }
  bool isB = (c0 >= 128);
  float b1v0 = 0.f, b1v1 = 0.f;
  if (isB) { b1v0 = b1[c0 - 128 + jl]; b1v1 = b1[c0 - 96 + jl]; }
#pragma unroll
  for (int q = 0; q < 16; ++q) {
    int r = (q & 3) + 8 * (q >> 2) + 4 * hi;
    int bl0 = row0 + r;
    if (!isB) {
      Aout[(size_t)bl0 * 128 + c0 + jl]      = a00[q];
      Aout[(size_t)bl0 * 128 + c0 + 32 + jl] = a01[q];
    } else {
      Bout[(size_t)bl0 * 128 + c0 - 128 + jl] = a00[q] + b1v0;
      Bout[(size_t)bl0 * 128 + c0 - 96 + jl]  = a01[q] + b1v1;
    }
  }
}

union BfPack { __bf16 h[16]; short8 v[2]; };

// ---- k2: main triangular-tile kernel, 8 i-rows per block ----
__global__ __launch_bounds__(256) void k2_main(const float* __restrict__ X,
                                               const unsigned short* __restrict__ WpT,
                                               const float* __restrict__ Aws,
                                               const float* __restrict__ Bws,
                                               const float* __restrict__ W2,
                                               const float* __restrict__ b2,
                                               float* __restrict__ out) {
  __shared__ __align__(16) unsigned short Mlds[2][32 * 128];  // 16 KB, double-buffered
  __shared__ __align__(16) float Xp[IPB][128];                // 4 KB: Xi panel
  __shared__ __align__(16) float Abias[IPB][128];             // 4 KB
  __shared__ __align__(16) float Bbias[IPB][128];             // 4 KB
  __shared__ __align__(16) float W2l[128];                    // 0.5 KB
  __shared__ float2 osum[IPB][4][32];                         // 8 KB: per-row slots
  __shared__ float valbuf[IPB][33];                           // 1 KB => ~37.5 KB total

  int bid = blockIdx.x;
  int q4 = bid & 3;                          // i-panel quarter within the 32-tile
  int tl = bid >> 2;
  int b = tl / NTRI;
  int t = tl - b * NTRI;
  int ti = 0;
  while (t >= NT - ti) { t -= NT - ti; ++ti; }
  int tj = ti + t;
  int gi0 = ti * 32, gj0 = tj * 32;
  int giBase = gi0 + q4 * IPB;

  int tid = threadIdx.x, w = tid >> 6, lane = tid & 63, jl = lane & 31, hi = lane >> 5;
  int dseg = tid >> 5;                      // 16-d slice owned for M-build
  int gj = gj0 + jl;
  const size_t rowX = (size_t)b * 1024;

  // ---- prologue: stage Xi panel + bias panels + W2 into LDS ----
  {
    int r = tid >> 5, c = (tid & 31) * 4;    // 8 rows x 128 cols, one float4/thread/panel
    const float* xp = X   + (rowX + giBase + r) * 128 + c;
    const float* ap = Aws + (rowX + giBase + r) * 128 + c;
    const float* bp = Bws + (rowX + giBase + r) * 128 + c;
    *(float4*)(&Xp[r][c])    = *(const float4*)(xp);
    *(float4*)(&Abias[r][c]) = *(const float4*)(ap);
    *(float4*)(&Bbias[r][c]) = *(const float4*)(bp);
    if (tid < 128) W2l[tid] = W2[tid];
  }

  // persistent per-thread state (j-side)
  float xj[16], bmj[16], ajv[16];
  {
    const float* xjp = X + (rowX + gj) * 128 + dseg * 16;
    *(float4*)(xj + 0)  = *(const float4*)(xjp + 0);
    *(float4*)(xj + 4)  = *(const float4*)(xjp + 4);
    *(float4*)(xj + 8)  = *(const float4*)(xjp + 8);
    *(float4*)(xj + 12) = *(const float4*)(xjp + 12);
  }
#pragma unroll
  for (int g = 0; g < 4; ++g) {
    int hb = 8 * g + 4 * hi + 32 * w;
    *(float4*)(bmj + 4 * g) = *(const float4*)(Bws + (rowX + gj) * 128 + hb);
    *(float4*)(ajv + 4 * g) = *(const float4*)(Aws + (rowX + gj) * 128 + hb);
  }
  short8 afrag[8];
#pragma unroll
  for (int s = 0; s < 8; ++s)
    afrag[s] = *(const short8*)(WpT + (size_t)(w * 32 + jl) * 128 + s * 16 + hi * 8);
  float b2s = b2[0];

  char* mB0 = (char*)Mlds[0];
  char* mB1 = (char*)Mlds[1];
  int rbase = jl * 256;
  int swz = (jl & 15) << 4;                  // 16-slot XOR involution (write==read)

  // build M(i): Xi slice from LDS broadcast * xj regs -> bf16 -> swizzled M buf
  auto writeM = [&](int i, char* mp) {
    const float* xip = &Xp[i][dseg * 16];
    float xv[16];
    *(float4*)(xv + 0)  = *(const float4*)(xip + 0);
    *(float4*)(xv + 4)  = *(const float4*)(xip + 4);
    *(float4*)(xv + 8)  = *(const float4*)(xip + 8);
    *(float4*)(xv + 12) = *(const float4*)(xip + 12);
    BfPack mb;
#pragma unroll
    for (int r = 0; r < 8; ++r) {
      f32x2 xa = { xv[2 * r], xv[2 * r + 1] };
      f32x2 xb = { xj[2 * r], xj[2 * r + 1] };
      f32x2 pr = xa * xb;
      mb.h[2 * r]     = (__bf16)pr[0];
      mb.h[2 * r + 1] = (__bf16)pr[1];
    }
    *(short8*)(mp + rbase + ((dseg * 32 + 0) ^ swz))  = mb.v[0];
    *(short8*)(mp + rbase + ((dseg * 32 + 16) ^ swz)) = mb.v[1];
  };
  auto mfmaTile = [&](const char* mr) -> f32x16 {
    f32x16 acc = (f32x16)0.0f;
    __builtin_amdgcn_s_setprio(1);           // T5: favor MFMA-feeding wave
#pragma unroll
    for (int s = 0; s < 8; ++s) {
      short8 bf = *(const short8*)(mr + rbase + (((2 * s + hi) * 16) ^ swz));
      acc = __builtin_amdgcn_mfma_f32_32x32x16_bf16(afrag[s], bf, acc, 0, 0, 0);
    }
    __builtin_amdgcn_s_setprio(0);
    return acc;
  };
  // epilogue of row r (acc in regs), biases via LDS broadcast; writes osum[r]
  auto epilogue = [&](const f32x16& acc, int r) {
    f32x2 o1v = { 0.f, 0.f }, o2v = { 0.f, 0.f };
#pragma unroll
    for (int k = 0; k < 8; ++k) {
      int hb = ((2 * k) & 3) + 8 * ((2 * k) >> 2) + 4 * hi + 32 * w;
      f32x2 aiv = *(const f32x2*)(&Abias[r][hb]);   // broadcast (uniform addr)
      f32x2 biv = *(const f32x2*)(&Bbias[r][hb]);
      f32x2 wv  = *(const f32x2*)(&W2l[hb]);
      f32x2 p   = { acc[2 * k], acc[2 * k + 1] };
      f32x2 b_j = { bmj[2 * k], bmj[2 * k + 1] };
      f32x2 a_j = { ajv[2 * k], ajv[2 * k + 1] };
      f32x2 g1 = gelu_2((p + aiv) + b_j);
      f32x2 g2 = gelu_2((p + a_j) + biv);
      o1v = __builtin_elementwise_fma(g1, wv, o1v);
      o2v = __builtin_elementwise_fma(g2, wv, o2v);
    }
    float o1 = o1v[0] + o1v[1], o2 = o2v[0] + o2v[1];
    o1 += __shfl_xor(o1, 32);
    o2 += __shfl_xor(o2, 32);
    if (lane < 32) osum[r][w][lane] = make_float2(o1, o2);
  };

  __syncthreads();                           // staging complete
  writeM(0, mB0);
  __syncthreads();                           // M(0) ready

  f32x16 accP;                               // acc of row i-1, carried

#pragma unroll 1
  for (int i = 0; i < IPB; ++i) {
    // MFMA chain(i) -> accC issues first (matrix pipe, post-barrier ds_reads)
    f32x16 accC = mfmaTile((i & 1) ? mB1 : mB0);
    // ds_write for M(i+1) issues next — lands during the epilogue below
    if (i + 1 < IPB) writeM(i + 1, ((i + 1) & 1) ? mB1 : mB0);
    // epilogue(row i-1): long VALU stream; barrier follows it
    if (i >= 1) epilogue(accP, i - 1);
    accP = accC;
    __syncthreads();
  }
  epilogue(accP, IPB - 1);                   // row 7; consumed after barrier
  __syncthreads();

  // ---- post-loop finalize: one output cell per thread ----
  {
    int r = tid >> 5;                        // 0..7
    int j = tid & 31;
    float2 p0 = osum[r][0][j], p1 = osum[r][1][j];
    float2 p2 = osum[r][2][j], p3 = osum[r][3][j];
    float s1 = p0.x + p1.x + p2.x + p3.x + b2s;
    float s2 = p0.y + p1.y + p2.y + p3.y + b2s;
    float v = 0.5f * (fmaxf(s1, 0.f) + fmaxf(s2, 0.f));
    int gi = giBase + r;
    if (ti == tj && gj0 + j == gi) v = 0.f;
    out[(rowX + gi) * 1024 + gj0 + j] = v;
    valbuf[r][j] = v;
  }
  __syncthreads();

  if (ti != tj && tid < 64) {                // coalesced transposed mirror flush
    int j = tid >> 1, i0 = (tid & 1) * 4;
    float4 v;
    v.x = valbuf[i0 + 0][j]; v.y = valbuf[i0 + 1][j];
    v.z = valbuf[i0 + 2][j]; v.w = valbuf[i0 + 3][j];
    *(float4*)(out + (rowX + gj0 + j) * 1024 + giBase + i0) = v;
  }
}

extern "C" void kernel_launch(void* const* d_in, const int* in_sizes, int n_in,
                              void* d_out, int out_size, void* d_ws, size_t ws_size,
                              hipStream_t stream) {
  (void)in_sizes; (void)n_in; (void)out_size; (void)ws_size;
  const float* X  = (const float*)d_in[0];   // (2,1024,128)
  const float* W1 = (const float*)d_in[1];   // (512,128)
  const float* b1 = (const float*)d_in[2];   // (128)
  const float* W2 = (const float*)d_in[3];   // (128,1)
  const float* b2 = (const float*)d_in[4];   // (1)
  float* out = (float*)d_out;                // (2,1024,1024)

  unsigned short* wsT = (unsigned short*)d_ws;
  unsigned short* WpT = wsT + 2 * 16384;
  float* Aws = (float*)((char*)d_ws + 98304);
  float* Bws = (float*)((char*)d_ws + 98304 + 1048576);

  k0_prep_w<<<192, 256, 0, stream>>>(W1, wsT);
  k1_ab<<<64, 256, 0, stream>>>(X, wsT, b1, Aws, Bws);
  k2_main<<<8 * NTRI, 256, 0, stream>>>(X, WpT, Aws, Bws, W2, b2, out);
}